// Round 14
// baseline (368.423 us; speedup 1.0000x reference)
//
#include <hip/hip_runtime.h>
#include <hip/hip_bf16.h>

typedef __hip_bfloat16 bf16;

#define NT 262144
#define ND 262144
#define EDT 2097152
#define ETT 1048576
#define NSLOT (2*NT)            // [0,NT)=d2t dst slots, [NT,2NT)=tt dst slots
#define NE_TOT (EDT+ETT)        // 3145728
#define NBKT 1024               // coarse buckets, bucket = slot>>9
#define SPB 512                 // slots per bucket
#define BCAP 3072               // per-bucket ebuf capacity (mean ~2048)
#define CH 8192                 // edges per scatter block (r7/r9 A/B: 8192 beats 4096)
#define NBLK_SCAT (NE_TOT/CH)   // 384
#define NBLK_STEM (NT/256)      // 1024
#define NBLK_MEGA (2*NBLK_STEM + NBLK_SCAT)

// ---- dual-dtype load/store: isbf==1 -> bf16, else fp32 ----
__device__ __forceinline__ float ldf(const void* p, long i, int isbf){
    if (isbf) return __bfloat162float(((const bf16*)p)[i]);
    return ((const float*)p)[i];
}
__device__ __forceinline__ void stf(void* p, int i, float v, int isbf){
    if (isbf) ((bf16*)p)[i] = __float2bfloat16(v);
    else      ((float*)p)[i] = v;
}
__device__ __forceinline__ float fin(float x){
    return (x==x && x>-3e38f && x<3e38f) ? x : 0.f;
}
// ---- bf16x2 pack/unpack ----
__device__ __forceinline__ unsigned pk2(float a, float b){
    bf16 ha = __float2bfloat16(a), hb = __float2bfloat16(b);
    unsigned short ua = *(unsigned short*)&ha, ub = *(unsigned short*)&hb;
    return ((unsigned)ub<<16) | (unsigned)ua;
}
__device__ __forceinline__ float ulo(unsigned u){ return __uint_as_float(u<<16); }
__device__ __forceinline__ float uhi(unsigned u){ return __uint_as_float(u & 0xffff0000u); }

// block-uniform dtype sniff (proven r2-r13)
__device__ __forceinline__ int detect_bf16(const void* xraw){
    const unsigned* r = (const unsigned*)xraw;
    int c = 0;
    #pragma unroll
    for (int i=0;i<16;i++){
        unsigned e = (r[i] >> 7) & 0xFFu;
        c += (e >= 116u && e <= 134u) ? 1 : 0;
    }
    return c > 8;
}

__device__ __forceinline__ float score8(uint4 u, const float* xr, const float* at){
    float s=0.f, m;
    m = ulo(u.x)+xr[0]; m = m>0.f?m:0.2f*m; s += m*at[0];
    m = uhi(u.x)+xr[1]; m = m>0.f?m:0.2f*m; s += m*at[1];
    m = ulo(u.y)+xr[2]; m = m>0.f?m:0.2f*m; s += m*at[2];
    m = uhi(u.y)+xr[3]; m = m>0.f?m:0.2f*m; s += m*at[3];
    m = ulo(u.z)+xr[4]; m = m>0.f?m:0.2f*m; s += m*at[4];
    m = uhi(u.z)+xr[5]; m = m>0.f?m:0.2f*m; s += m*at[5];
    m = ulo(u.w)+xr[6]; m = m>0.f?m:0.2f*m; s += m*at[6];
    m = uhi(u.w)+xr[7]; m = m>0.f?m:0.2f*m; s += m*at[7];
    return s;
}
__device__ __forceinline__ void acc8(uint4 u, float a, float* acc){
    acc[0] += a*ulo(u.x); acc[1] += a*uhi(u.x);
    acc[2] += a*ulo(u.y); acc[3] += a*uhi(u.y);
    acc[4] += a*ulo(u.z); acc[5] += a*uhi(u.z);
    acc[6] += a*ulo(u.w); acc[7] += a*uhi(u.w);
}

// ---------------- mega kernel: scatter first, then both stems ----------------
// blocks [0,384): scatter   [384,1408): task stem   [1408,2432): data stem
union SmemMega {
    struct { float sW[192], sb[16], sg[16], sbt[16], sWl[512]; } st;   // task stem
    struct { float sW[80],  sb[16], sg[16], sbt[16], sWl[512]; } sd;   // data stem
    struct { int shc[NBKT], sloff[NBKT], slcur[NBKT], spart[256];
             unsigned stage[CH]; } sc;                                  // scatter (45KB)
};

__global__ __launch_bounds__(256) void mega_kernel(
    const void* __restrict__ x_tasks, const void* __restrict__ x_data,
    const void* __restrict__ stem_t_W, const void* __restrict__ stem_t_b,
    const void* __restrict__ ln_t_g, const void* __restrict__ ln_t_b,
    const void* __restrict__ stem_d_W, const void* __restrict__ stem_d_b,
    const void* __restrict__ ln_d_g, const void* __restrict__ ln_d_b,
    const void* __restrict__ tt_Wl, const void* __restrict__ dt_Wl,
    float* __restrict__ xt, unsigned* __restrict__ xl_tt, unsigned* __restrict__ xl_dt,
    const int* __restrict__ ei_dt, const int* __restrict__ mask_dt,
    const int* __restrict__ ei_tt,
    int* __restrict__ bktCur, unsigned* __restrict__ ebuf)
{
    __shared__ SmemMega sm;
    int t = threadIdx.x;
    int blk = blockIdx.x;

    if (blk < NBLK_SCAT){
        // ---- bucket scatter (LDS-staged), packed edge: src | dloc<<18 ----
        long e0 = (long)blk * CH;
        for (int b=t; b<NBKT; b+=256) sm.sc.shc[b]=0;
        __syncthreads();
        for (int i=t; i<CH; i+=256){
            long e = e0 + i;
            int slot, keep;
            if (e < EDT){ keep = mask_dt[e]; slot = ei_dt[EDT+e]; }
            else { long e2 = e-EDT; keep = 1; slot = NT + ei_tt[ETT+e2]; }
            if (keep) atomicAdd(&sm.sc.shc[slot>>9], 1);
        }
        __syncthreads();
        int b4 = t*4;
        int a0=sm.sc.shc[b4], a1=sm.sc.shc[b4+1], a2=sm.sc.shc[b4+2], a3=sm.sc.shc[b4+3];
        int lsum = a0+a1+a2+a3;
        // wave-shfl inclusive scan (register-only, no barriers) + 1-barrier
        // cross-wave combine (r13; equal to 16-barrier scan, simpler).
        int lane = t & 63, wid = t >> 6;
        int scan = lsum;
        #pragma unroll
        for (int off=1; off<64; off<<=1){
            int n = __shfl_up(scan, off);
            scan = (lane >= off) ? scan + n : scan;
        }
        if (lane == 63) sm.sc.spart[wid] = scan;
        __syncthreads();
        int wt0 = sm.sc.spart[0], wt1 = sm.sc.spart[1],
            wt2 = sm.sc.spart[2], wt3 = sm.sc.spart[3];
        int wbase = ((wid>0)?wt0:0) + ((wid>1)?wt1:0) + ((wid>2)?wt2:0);
        int totKept = wt0 + wt1 + wt2 + wt3;
        int run = wbase + scan - lsum;   // exclusive prefix of lsum
        sm.sc.sloff[b4]=run;   sm.sc.slcur[b4]=run;   run+=a0;
        sm.sc.sloff[b4+1]=run; sm.sc.slcur[b4+1]=run; run+=a1;
        sm.sc.sloff[b4+2]=run; sm.sc.slcur[b4+2]=run; run+=a2;
        sm.sc.sloff[b4+3]=run; sm.sc.slcur[b4+3]=run;
        if (a0>0) sm.sc.shc[b4]   = atomicAdd(&bktCur[b4],   a0);
        if (a1>0) sm.sc.shc[b4+1] = atomicAdd(&bktCur[b4+1], a1);
        if (a2>0) sm.sc.shc[b4+2] = atomicAdd(&bktCur[b4+2], a2);
        if (a3>0) sm.sc.shc[b4+3] = atomicAdd(&bktCur[b4+3], a3);
        __syncthreads();
        for (int i=t; i<CH; i+=256){
            long e = e0 + i;
            int slot, keep, s;
            if (e < EDT){ keep = mask_dt[e]; s = ei_dt[e]; slot = ei_dt[EDT+e]; }
            else { long e2 = e-EDT; keep = 1; s = ei_tt[e2]; slot = NT + ei_tt[ETT+e2]; }
            if (keep){
                int b = slot>>9;
                int pos = atomicAdd(&sm.sc.slcur[b], 1);
                sm.sc.stage[pos] = (unsigned)s | ((unsigned)(slot & 511) << 18);
            }
        }
        __syncthreads();
        for (int i=t; i<totKept; i+=256){
            int lo=0, hi=NBKT-1;
            while (lo<hi){ int mid=(lo+hi+1)>>1; if (sm.sc.sloff[mid]<=i) lo=mid; else hi=mid-1; }
            int pos = sm.sc.shc[lo] + (i - sm.sc.sloff[lo]);
            if (pos < BCAP)
                ebuf[(long)lo*BCAP + pos] = sm.sc.stage[i];
        }
        return;
    }
    int isbf = detect_bf16(x_tasks);
    if (blk < NBLK_SCAT + NBLK_STEM){
        // ---- task stem: xt + fused @tt_Wl -> xl_tt ----
        if (t < 192) sm.st.sW[t] = ldf(stem_t_W, t, isbf);
        if (t < 16){ sm.st.sb[t]=ldf(stem_t_b,t,isbf); sm.st.sg[t]=ldf(ln_t_g,t,isbf); sm.st.sbt[t]=ldf(ln_t_b,t,isbf); }
        sm.st.sWl[t]     = ldf(tt_Wl, t,     isbf);
        sm.st.sWl[t+256] = ldf(tt_Wl, t+256, isbf);
        __syncthreads();
        long i = (long)(blk - NBLK_SCAT)*256 + t;
        float f[12];
        if (isbf){
            const uint2* p = (const uint2*)((const char*)x_tasks + i*24);
            uint2 w0=p[0], w1=p[1], w2=p[2];
            unsigned ww[6] = {w0.x,w0.y,w1.x,w1.y,w2.x,w2.y};
            #pragma unroll
            for (int k=0;k<6;k++){ f[2*k]=ulo(ww[k]); f[2*k+1]=uhi(ww[k]); }
        } else {
            const float4* p = (const float4*)((const char*)x_tasks + i*48);
            float4 a=p[0], b2=p[1], c2=p[2];
            f[0]=a.x;  f[1]=a.y;  f[2]=a.z;  f[3]=a.w;
            f[4]=b2.x; f[5]=b2.y; f[6]=b2.z; f[7]=b2.w;
            f[8]=c2.x; f[9]=c2.y; f[10]=c2.z; f[11]=c2.w;
        }
        float h[16];
        #pragma unroll
        for (int c=0;c<16;c++){
            float a = sm.st.sb[c];
            #pragma unroll
            for (int k=0;k<12;k++) a += f[k]*sm.st.sW[k*16+c];
            h[c]=a;
        }
        float mu=0.f;
        #pragma unroll
        for (int c=0;c<16;c++) mu += h[c];
        mu *= (1.f/16.f);
        float var=0.f;
        #pragma unroll
        for (int c=0;c<16;c++){ float d=h[c]-mu; var += d*d; }
        var *= (1.f/16.f);
        float inv = rsqrtf(var + 1e-5f);
        float v[16];
        #pragma unroll
        for (int c=0;c<16;c++){
            float y = sm.st.sg[c]*(h[c]-mu)*inv + sm.st.sbt[c];
            v[c] = fin((y>0.f) ? y : 0.01f*y);
        }
        float4* xp = (float4*)(xt + i*16);
        #pragma unroll
        for (int q=0;q<4;q++) xp[q] = make_float4(v[q*4],v[q*4+1],v[q*4+2],v[q*4+3]);
        float o[32];
        #pragma unroll
        for (int c=0;c<32;c++) o[c]=0.f;
        #pragma unroll
        for (int k=0;k<16;k++){
            float xv=v[k];
            #pragma unroll
            for (int c=0;c<32;c++) o[c] += xv*sm.st.sWl[k*32+c];
        }
        #pragma unroll
        for (int c=0;c<32;c++) o[c] = fin(o[c]);
        uint4* op = (uint4*)(xl_tt + i*16);
        #pragma unroll
        for (int q=0;q<4;q++)
            op[q] = make_uint4(pk2(o[q*8],o[q*8+1]), pk2(o[q*8+2],o[q*8+3]),
                               pk2(o[q*8+4],o[q*8+5]), pk2(o[q*8+6],o[q*8+7]));
    } else {
        // ---- data stem: fused @dt_Wl -> xl_dt ----
        if (t < 80) sm.sd.sW[t] = ldf(stem_d_W, t, isbf);
        if (t < 16){ sm.sd.sb[t]=ldf(stem_d_b,t,isbf); sm.sd.sg[t]=ldf(ln_d_g,t,isbf); sm.sd.sbt[t]=ldf(ln_d_b,t,isbf); }
        sm.sd.sWl[t]     = ldf(dt_Wl, t,     isbf);
        sm.sd.sWl[t+256] = ldf(dt_Wl, t+256, isbf);
        __syncthreads();
        long i = (long)(blk - NBLK_SCAT - NBLK_STEM)*256 + t;
        float f[5];
        #pragma unroll
        for (int k=0;k<5;k++) f[k] = ldf(x_data, i*5+k, isbf);
        float h[16];
        #pragma unroll
        for (int c=0;c<16;c++){
            float a = sm.sd.sb[c];
            #pragma unroll
            for (int k=0;k<5;k++) a += f[k]*sm.sd.sW[k*16+c];
            h[c]=a;
        }
        float mu=0.f;
        #pragma unroll
        for (int c=0;c<16;c++) mu += h[c];
        mu *= (1.f/16.f);
        float var=0.f;
        #pragma unroll
        for (int c=0;c<16;c++){ float d=h[c]-mu; var += d*d; }
        var *= (1.f/16.f);
        float inv = rsqrtf(var + 1e-5f);
        float v[16];
        #pragma unroll
        for (int c=0;c<16;c++){
            float y = sm.sd.sg[c]*(h[c]-mu)*inv + sm.sd.sbt[c];
            v[c] = (y>0.f) ? y : 0.01f*y;
        }
        float o[32];
        #pragma unroll
        for (int c=0;c<32;c++) o[c]=0.f;
        #pragma unroll
        for (int k=0;k<16;k++){
            float xv=v[k];
            #pragma unroll
            for (int c=0;c<32;c++) o[c] += xv*sm.sd.sWl[k*32+c];
        }
        #pragma unroll
        for (int c=0;c<32;c++) o[c] = fin(o[c]);
        uint4* op = (uint4*)(xl_dt + i*16);
        #pragma unroll
        for (int q=0;q<4;q++)
            op[q] = make_uint4(pk2(o[q*8],o[q*8+1]), pk2(o[q*8+2],o[q*8+3]),
                               pk2(o[q*8+4],o[q*8+5]), pk2(o[q*8+6],o[q*8+7]));
    }
}

// ---------------- phase 2: per-bucket LDS CSR + head-serial GAT aggregation ----------------
// r7 structure with the unroll extended 2x -> 4x (8 independent 16B loads in
// flight; same Little's-law mechanism as the r7 win). Falls through 4x -> 2x -> 1x.
// NO other code may be added to this kernel (r1/r4/r11 regalloc lessons).
__global__ __launch_bounds__(256) void bucket_aggregate_kernel(
    const int* __restrict__ bktCur, const unsigned* __restrict__ ebuf,
    const float* __restrict__ xt,
    const unsigned* __restrict__ xl_dt, const unsigned* __restrict__ xl_tt,
    const void* __restrict__ dt_Wr, const void* __restrict__ tt_Wr,
    const void* __restrict__ dt_att, const void* __restrict__ tt_att,
    float* __restrict__ agg, const void* __restrict__ x_tasks_raw)
{
    __shared__ float sWr[512], satt[32];
    __shared__ int scnt[SPB], soff[SPB], scur[SPB], spart[256];
    __shared__ unsigned slist[BCAP];
    __shared__ float sspill[256*17];
    int t = threadIdx.x;
    int b = blockIdx.x;
    int which = (b >= NBKT/2);
    int isbf = detect_bf16(x_tasks_raw);
    const void* Wr  = which ? tt_Wr  : dt_Wr;
    const void* att = which ? tt_att : dt_att;
    sWr[t]     = ldf(Wr, t,     isbf);
    sWr[t+256] = ldf(Wr, t+256, isbf);
    if (t < 32) satt[t] = ldf(att, t, isbf);
    scnt[t] = 0; scnt[t+256] = 0;
    __syncthreads();
    int base = b*BCAP;
    int ecnt = bktCur[b];
    if (ecnt > BCAP) ecnt = BCAP;
    for (int i=t; i<ecnt; i+=256)
        atomicAdd(&scnt[ebuf[base+i] >> 18], 1);
    __syncthreads();
    int c0 = scnt[2*t], c1 = scnt[2*t+1];
    int ls = c0 + c1;
    spart[t] = ls;
    __syncthreads();
    for (int off=1; off<256; off<<=1){
        int x = spart[t];
        int add = (t>=off) ? spart[t-off] : 0;
        __syncthreads();
        spart[t] = x + add;
        __syncthreads();
    }
    int run = spart[t] - ls;
    soff[2*t] = run; scur[2*t] = run;
    soff[2*t+1] = run + c0; scur[2*t+1] = run + c0;
    __syncthreads();
    for (int i=t; i<ecnt; i+=256){
        unsigned p = ebuf[base+i];
        int pos = atomicAdd(&scur[p >> 18], 1);
        slist[pos] = p & 0x3FFFFu;
    }
    __syncthreads();
    const unsigned* xl = which ? xl_tt : xl_dt;
    #pragma unroll 1
    for (int half=0; half<2; half++){
        int dloc = t + half*256;
        long slot = (long)b*SPB + dloc;
        long d = which ? slot - NT : slot;
        int e0 = soff[dloc], e1 = scur[dloc];
        #pragma unroll 1
        for (int head=0; head<2; head++){
            const float4* xp = (const float4*)(xt + d*16);
            float4 x0=xp[0], x1=xp[1], x2=xp[2], x3=xp[3];
            float xtv[16] = {x0.x,x0.y,x0.z,x0.w, x1.x,x1.y,x1.z,x1.w,
                             x2.x,x2.y,x2.z,x2.w, x3.x,x3.y,x3.z,x3.w};
            float xr[16];
            #pragma unroll
            for (int c=0;c<16;c++) xr[c]=0.f;
            #pragma unroll
            for (int k=0;k<16;k++){
                float xv=xtv[k];
                #pragma unroll
                for (int c=0;c<16;c++) xr[c] += xv*sWr[k*32 + head*16 + c];
            }
            const float* at = satt + head*16;
            float acc[16];
            #pragma unroll
            for (int c=0;c<16;c++) acc[c]=0.f;
            float den=0.f;
            int e = e0;
            // 4x unrolled gather: 8 independent global loads in flight
            for (; e+3 < e1; e += 4){
                long sA = slist[e],   sB = slist[e+1];
                long sC = slist[e+2], sD = slist[e+3];
                const uint4* pA = (const uint4*)(xl + sA*16 + head*8);
                const uint4* pB = (const uint4*)(xl + sB*16 + head*8);
                const uint4* pC = (const uint4*)(xl + sC*16 + head*8);
                const uint4* pD = (const uint4*)(xl + sD*16 + head*8);
                uint4 ua0 = pA[0], ua1 = pA[1];
                uint4 ub0 = pB[0], ub1 = pB[1];
                uint4 uc0 = pC[0], uc1 = pC[1];
                uint4 ud0 = pD[0], ud1 = pD[1];
                float scA = score8(ua0, xr, at) + score8(ua1, xr+8, at+8);
                float scB = score8(ub0, xr, at) + score8(ub1, xr+8, at+8);
                float scC = score8(uc0, xr, at) + score8(uc1, xr+8, at+8);
                float scD = score8(ud0, xr, at) + score8(ud1, xr+8, at+8);
                float aA = __expf(fminf(fin(scA), 60.f));
                float aB = __expf(fminf(fin(scB), 60.f));
                float aC = __expf(fminf(fin(scC), 60.f));
                float aD = __expf(fminf(fin(scD), 60.f));
                den += (aA + aB) + (aC + aD);
                acc8(ua0, aA, acc); acc8(ua1, aA, acc+8);
                acc8(ub0, aB, acc); acc8(ub1, aB, acc+8);
                acc8(uc0, aC, acc); acc8(uc1, aC, acc+8);
                acc8(ud0, aD, acc); acc8(ud1, aD, acc+8);
            }
            // 2x body (r7)
            for (; e+1 < e1; e += 2){
                long sA = slist[e], sB = slist[e+1];
                const uint4* pA = (const uint4*)(xl + sA*16 + head*8);
                const uint4* pB = (const uint4*)(xl + sB*16 + head*8);
                uint4 ua0 = pA[0], ua1 = pA[1];
                uint4 ub0 = pB[0], ub1 = pB[1];
                float scA = score8(ua0, xr, at) + score8(ua1, xr+8, at+8);
                float scB = score8(ub0, xr, at) + score8(ub1, xr+8, at+8);
                float aA = __expf(fminf(fin(scA), 60.f));
                float aB = __expf(fminf(fin(scB), 60.f));
                den += aA + aB;
                acc8(ua0, aA, acc); acc8(ua1, aA, acc+8);
                acc8(ub0, aB, acc); acc8(ub1, aB, acc+8);
            }
            if (e < e1){
                long s = slist[e];
                const uint4* p = (const uint4*)(xl + s*16 + head*8);
                uint4 u0 = p[0], u1 = p[1];
                float sc = score8(u0, xr, at) + score8(u1, xr+8, at+8);
                float a = __expf(fminf(fin(sc), 60.f));
                den += a;
                acc8(u0, a, acc); acc8(u1, a, acc+8);
            }
            float id = 1.f/fmaxf(den, 1e-16f);
            if (head==0){
                #pragma unroll
                for (int c=0;c<16;c++) sspill[t*17+c] = acc[c]*id;
            } else {
                float4* op = (float4*)(agg + slot*16);
                #pragma unroll
                for (int q=0;q<4;q++){
                    float v[4];
                    #pragma unroll
                    for (int j=0;j<4;j++)
                        v[j] = fin(0.5f*(sspill[t*17+q*4+j] + acc[q*4+j]*id));
                    op[q] = make_float4(v[0],v[1],v[2],v[3]);
                }
            }
        }
    }
}

__device__ __forceinline__ void ln_act16(const float* v, const float* g, const float* b, float* o){
    float mu=0.f;
    #pragma unroll
    for (int c=0;c<16;c++) mu += v[c];
    mu *= (1.f/16.f);
    float var=0.f;
    #pragma unroll
    for (int c=0;c<16;c++){ float d=v[c]-mu; var += d*d; }
    var *= (1.f/16.f);
    float inv = rsqrtf(var + 1e-5f);
    #pragma unroll
    for (int c=0;c<16;c++){
        float y = g[c]*(v[c]-mu)*inv + b[c];
        o[c] = (y>0.f) ? y : 0.01f*y;
    }
}

// ---------------- fuse + pooling + last-block finish ----------------
__global__ __launch_bounds__(256) void fuse_pool_kernel(
    const float* __restrict__ xt,
    const float* __restrict__ agg_dt, const float* __restrict__ agg_tt,
    const void* __restrict__ dt_res, const void* __restrict__ dt_bias,
    const void* __restrict__ tt_res, const void* __restrict__ tt_bias,
    const void* __restrict__ ln1g, const void* __restrict__ ln1b,
    const void* __restrict__ ln2g, const void* __restrict__ ln2b,
    const int* __restrict__ b_tasks, const int* __restrict__ ptrg,
    float* __restrict__ pool_sums, float* __restrict__ pool_cnt,
    int* __restrict__ done,
    void* __restrict__ out, const void* __restrict__ x_tasks_raw)
{
    int isbf = detect_bf16(x_tasks_raw);
    __shared__ float sdt[256], stt[256], sdb[16], stb[16], s1g[16], s1b[16], s2g[16], s2b[16];
    __shared__ float swave[4*48];
    __shared__ int sptr[16];
    __shared__ int s_nonuni;
    __shared__ int s_last;
    int t = threadIdx.x;
    sdt[t] = ldf(dt_res, t, isbf);
    stt[t] = ldf(tt_res, t, isbf);
    if (t < 16){
        sdb[t]=ldf(dt_bias,t,isbf); stb[t]=ldf(tt_bias,t,isbf);
        s1g[t]=ldf(ln1g,t,isbf); s1b[t]=ldf(ln1b,t,isbf);
        s2g[t]=ldf(ln2g,t,isbf); s2b[t]=ldf(ln2b,t,isbf);
        sptr[t]=ptrg[t];
    }
    if (t==0) s_nonuni = 0;
    __syncthreads();
    long i = blockIdx.x*256 + t;
    const float4* xp = (const float4*)(xt + i*16);
    float4 x0=xp[0], x1=xp[1], x2=xp[2], x3=xp[3];
    float vals[48];
    float* xv   = vals;
    float* tupd = vals+16;
    float* dupd = vals+32;
    xv[0]=x0.x; xv[1]=x0.y; xv[2]=x0.z; xv[3]=x0.w;
    xv[4]=x1.x; xv[5]=x1.y; xv[6]=x1.z; xv[7]=x1.w;
    xv[8]=x2.x; xv[9]=x2.y; xv[10]=x2.z; xv[11]=x2.w;
    xv[12]=x3.x; xv[13]=x3.y; xv[14]=x3.z; xv[15]=x3.w;
    {
        const float* ag = agg_dt + i*16;
        float v[16];
        #pragma unroll
        for (int c=0;c<16;c++){
            float r = sdb[c];
            #pragma unroll
            for (int k=0;k<16;k++) r += xv[k]*sdt[k*16+c];
            v[c] = fin(ag[c] + r);
        }
        ln_act16(v, s1g, s1b, dupd);
    }
    {
        const float* ag = agg_tt + i*16;
        float v[16];
        #pragma unroll
        for (int c=0;c<16;c++){
            float r = stb[c];
            #pragma unroll
            for (int k=0;k<16;k++) r += xv[k]*stt[k*16+c];
            v[c] = fin(ag[c] + r);
        }
        ln_act16(v, s2g, s2b, tupd);
    }
    #pragma unroll
    for (int j=0;j<48;j++) vals[j] = fin(vals[j]);
    #pragma unroll
    for (int g=0; g<16; g++){
        if (i == sptr[g]){
            for (int j=0;j<48;j++) stf(out, g*96+j, vals[j], isbf);
        }
    }
    int gi = b_tasks[i];
    int g0 = b_tasks[blockIdx.x*256];
    if (gi != g0) s_nonuni = 1;
    __syncthreads();
    if (s_nonuni){
        for (int j=0;j<48;j++) atomicAdd(&pool_sums[gi*48+j], vals[j]);
        atomicAdd(&pool_cnt[gi], 1.f);
    } else {
        int lane = t & 63, wid = t >> 6;
        #pragma unroll
        for (int j=0;j<48;j++){
            float v = vals[j];
            v += __shfl_down(v, 32);
            v += __shfl_down(v, 16);
            v += __shfl_down(v, 8);
            v += __shfl_down(v, 4);
            v += __shfl_down(v, 2);
            v += __shfl_down(v, 1);
            if (lane==0) swave[wid*48+j] = v;
        }
        __syncthreads();
        if (t < 48){
            float s = swave[t] + swave[48+t] + swave[96+t] + swave[144+t];
            atomicAdd(&pool_sums[g0*48+t], s);
        }
        if (t == 0) atomicAdd(&pool_cnt[g0], 256.f);
    }
    // last-block-done: final block computes the 768 pooled means
    __syncthreads();
    if (t == 0){
        __threadfence();
        s_last = (atomicAdd(done, 1) == gridDim.x - 1) ? 1 : 0;
    }
    __syncthreads();
    if (s_last){
        __threadfence();
        for (int j = t; j < 768; j += 256){
            int g = j/48, c = j - g*48;
            stf(out, g*96+48+c, fin(pool_sums[g*48+c]/fmaxf(pool_cnt[g],1.f)), isbf);
        }
    }
}

extern "C" void kernel_launch(void* const* d_in, const int* in_sizes, int n_in,
                              void* d_out, int out_size, void* d_ws, size_t ws_size,
                              hipStream_t stream)
{
    const void* x_tasks  = d_in[0];
    const void* x_data   = d_in[1];
    const void* stem_t_W = d_in[2];
    const void* stem_t_b = d_in[3];
    const void* stem_d_W = d_in[4];
    const void* stem_d_b = d_in[5];
    const void* ln_t_g   = d_in[6];
    const void* ln_t_b   = d_in[7];
    const void* ln_d_g   = d_in[8];
    const void* ln_d_b   = d_in[9];
    const void* dt_Wl    = d_in[10];
    const void* dt_Wr    = d_in[11];
    const void* dt_att   = d_in[12];
    const void* dt_res   = d_in[13];
    const void* dt_bias  = d_in[14];
    const void* tt_Wl    = d_in[15];
    const void* tt_Wr    = d_in[16];
    const void* tt_att   = d_in[17];
    const void* tt_res   = d_in[18];
    const void* tt_bias  = d_in[19];
    const void* ln1_g    = d_in[20];
    const void* ln1_b    = d_in[21];
    const void* ln2_g    = d_in[22];
    const void* ln2_b    = d_in[23];
    const int*  ei_dt    = (const int*)d_in[24];
    const int*  mask_dt  = (const int*)d_in[25];
    const int*  ei_tt    = (const int*)d_in[26];
    const int*  b_tasks  = (const int*)d_in[27];
    const int*  ptrg     = (const int*)d_in[28];

    char* w = (char*)d_ws;
    const size_t MB = 1ull<<20;
    float*    xt        = (float*)(w);              // 16 MB  [NT,16] fp32
    unsigned* xl_dt     = (unsigned*)(w + 16*MB);   // 16 MB  [ND,16] bf16x2-packed
    unsigned* xl_tt     = (unsigned*)(w + 32*MB);   // 16 MB  [NT,16] bf16x2-packed
    float*    agg       = (float*)(w + 48*MB);      // 32 MB  [NSLOT,16] fp32
    unsigned* ebuf      = (unsigned*)(w + 80*MB);   // 12.6 MB (NBKT*BCAP) + slack
    // contiguous control block (zeroed by one memset):
    int*      bktCur    = (int*)  (w + 93*MB);              // 4096 B (relative cursors)
    float*    pool_sums = (float*)(w + 93*MB + 4096);       // 3072 B
    float*    pool_cnt  = (float*)(w + 93*MB + 4096 + 3072);// 64 B
    int*      done      = (int*)  (w + 93*MB + 7232);       // 4 B

    hipMemsetAsync(w + 93*MB, 0, 7296, stream);

    // mega: scatter blocks dispatched first, stems backfill behind
    mega_kernel<<<NBLK_MEGA, 256, 0, stream>>>(
        x_tasks, x_data, stem_t_W, stem_t_b, ln_t_g, ln_t_b,
        stem_d_W, stem_d_b, ln_d_g, ln_d_b, tt_Wl, dt_Wl,
        xt, xl_tt, xl_dt, ei_dt, mask_dt, ei_tt, bktCur, ebuf);

    // per-bucket LDS CSR + head-serial aggregation, 4x/2x/1x unrolled gather
    bucket_aggregate_kernel<<<NBKT, 256, 0, stream>>>(bktCur, ebuf, xt, xl_dt, xl_tt,
        dt_Wr, tt_Wr, dt_att, tt_att, agg, x_tasks);

    // fuse + pool + output (finish folded in via last-block-done)
    fuse_pool_kernel<<<NT/256, 256, 0, stream>>>(xt, agg, agg + (long)NT*16,
        dt_res, dt_bias, tt_res, tt_bias, ln1_g, ln1_b, ln2_g, ln2_b,
        b_tasks, ptrg, pool_sums, pool_cnt, done, d_out, x_tasks);
}

// Round 15
// 364.139 us; speedup vs baseline: 1.0118x; 1.0118x over previous
//
#include <hip/hip_runtime.h>
#include <hip/hip_bf16.h>

typedef __hip_bfloat16 bf16;

#define NT 262144
#define ND 262144
#define EDT 2097152
#define ETT 1048576
#define NSLOT (2*NT)            // [0,NT)=d2t dst slots, [NT,2NT)=tt dst slots
#define NE_TOT (EDT+ETT)        // 3145728
#define NBKT 1024               // coarse buckets, bucket = slot>>9
#define SPB 512                 // slots per bucket
#define BCAP 3072               // per-bucket ebuf capacity (mean ~2048)
#define CH 8192                 // edges per scatter block (r7/r9 A/B: 8192 beats 4096)
#define NBLK_SCAT (NE_TOT/CH)   // 384
#define NBLK_STEM (NT/256)      // 1024
#define NBLK_MEGA (2*NBLK_STEM + NBLK_SCAT)

// ---- dual-dtype load/store: isbf==1 -> bf16, else fp32 ----
__device__ __forceinline__ float ldf(const void* p, long i, int isbf){
    if (isbf) return __bfloat162float(((const bf16*)p)[i]);
    return ((const float*)p)[i];
}
__device__ __forceinline__ void stf(void* p, int i, float v, int isbf){
    if (isbf) ((bf16*)p)[i] = __float2bfloat16(v);
    else      ((float*)p)[i] = v;
}
__device__ __forceinline__ float fin(float x){
    return (x==x && x>-3e38f && x<3e38f) ? x : 0.f;
}
// ---- bf16x2 pack/unpack ----
__device__ __forceinline__ unsigned pk2(float a, float b){
    bf16 ha = __float2bfloat16(a), hb = __float2bfloat16(b);
    unsigned short ua = *(unsigned short*)&ha, ub = *(unsigned short*)&hb;
    return ((unsigned)ub<<16) | (unsigned)ua;
}
__device__ __forceinline__ float ulo(unsigned u){ return __uint_as_float(u<<16); }
__device__ __forceinline__ float uhi(unsigned u){ return __uint_as_float(u & 0xffff0000u); }

// block-uniform dtype sniff (proven r2-r14)
__device__ __forceinline__ int detect_bf16(const void* xraw){
    const unsigned* r = (const unsigned*)xraw;
    int c = 0;
    #pragma unroll
    for (int i=0;i<16;i++){
        unsigned e = (r[i] >> 7) & 0xFFu;
        c += (e >= 116u && e <= 134u) ? 1 : 0;
    }
    return c > 8;
}

__device__ __forceinline__ float score8(uint4 u, const float* xr, const float* at){
    float s=0.f, m;
    m = ulo(u.x)+xr[0]; m = m>0.f?m:0.2f*m; s += m*at[0];
    m = uhi(u.x)+xr[1]; m = m>0.f?m:0.2f*m; s += m*at[1];
    m = ulo(u.y)+xr[2]; m = m>0.f?m:0.2f*m; s += m*at[2];
    m = uhi(u.y)+xr[3]; m = m>0.f?m:0.2f*m; s += m*at[3];
    m = ulo(u.z)+xr[4]; m = m>0.f?m:0.2f*m; s += m*at[4];
    m = uhi(u.z)+xr[5]; m = m>0.f?m:0.2f*m; s += m*at[5];
    m = ulo(u.w)+xr[6]; m = m>0.f?m:0.2f*m; s += m*at[6];
    m = uhi(u.w)+xr[7]; m = m>0.f?m:0.2f*m; s += m*at[7];
    return s;
}
__device__ __forceinline__ void acc8(uint4 u, float a, float* acc){
    acc[0] += a*ulo(u.x); acc[1] += a*uhi(u.x);
    acc[2] += a*ulo(u.y); acc[3] += a*uhi(u.y);
    acc[4] += a*ulo(u.z); acc[5] += a*uhi(u.z);
    acc[6] += a*ulo(u.w); acc[7] += a*uhi(u.w);
}

// ---------------- mega kernel: scatter first, then both stems ----------------
// blocks [0,384): scatter   [384,1408): task stem   [1408,2432): data stem
union SmemMega {
    struct { float sW[192], sb[16], sg[16], sbt[16], sWl[512]; } st;   // task stem
    struct { float sW[80],  sb[16], sg[16], sbt[16], sWl[512]; } sd;   // data stem
    struct { int shc[NBKT], sloff[NBKT], slcur[NBKT], spart[256];
             unsigned stage[CH]; } sc;                                  // scatter (45KB)
};

__global__ __launch_bounds__(256) void mega_kernel(
    const void* __restrict__ x_tasks, const void* __restrict__ x_data,
    const void* __restrict__ stem_t_W, const void* __restrict__ stem_t_b,
    const void* __restrict__ ln_t_g, const void* __restrict__ ln_t_b,
    const void* __restrict__ stem_d_W, const void* __restrict__ stem_d_b,
    const void* __restrict__ ln_d_g, const void* __restrict__ ln_d_b,
    const void* __restrict__ tt_Wl, const void* __restrict__ dt_Wl,
    float* __restrict__ xt, unsigned* __restrict__ xl_tt, unsigned* __restrict__ xl_dt,
    const int* __restrict__ ei_dt, const int* __restrict__ mask_dt,
    const int* __restrict__ ei_tt,
    int* __restrict__ bktCur, unsigned* __restrict__ ebuf)
{
    __shared__ SmemMega sm;
    int t = threadIdx.x;
    int blk = blockIdx.x;

    if (blk < NBLK_SCAT){
        // ---- bucket scatter (LDS-staged), packed edge: src | dloc<<18 ----
        long e0 = (long)blk * CH;
        for (int b=t; b<NBKT; b+=256) sm.sc.shc[b]=0;
        __syncthreads();
        for (int i=t; i<CH; i+=256){
            long e = e0 + i;
            int slot, keep;
            if (e < EDT){ keep = mask_dt[e]; slot = ei_dt[EDT+e]; }
            else { long e2 = e-EDT; keep = 1; slot = NT + ei_tt[ETT+e2]; }
            if (keep) atomicAdd(&sm.sc.shc[slot>>9], 1);
        }
        __syncthreads();
        int b4 = t*4;
        int a0=sm.sc.shc[b4], a1=sm.sc.shc[b4+1], a2=sm.sc.shc[b4+2], a3=sm.sc.shc[b4+3];
        int lsum = a0+a1+a2+a3;
        // wave-shfl inclusive scan (register-only, no barriers) + 1-barrier
        // cross-wave combine (r13; equal to 16-barrier scan, simpler).
        int lane = t & 63, wid = t >> 6;
        int scan = lsum;
        #pragma unroll
        for (int off=1; off<64; off<<=1){
            int n = __shfl_up(scan, off);
            scan = (lane >= off) ? scan + n : scan;
        }
        if (lane == 63) sm.sc.spart[wid] = scan;
        __syncthreads();
        int wt0 = sm.sc.spart[0], wt1 = sm.sc.spart[1],
            wt2 = sm.sc.spart[2], wt3 = sm.sc.spart[3];
        int wbase = ((wid>0)?wt0:0) + ((wid>1)?wt1:0) + ((wid>2)?wt2:0);
        int totKept = wt0 + wt1 + wt2 + wt3;
        int run = wbase + scan - lsum;   // exclusive prefix of lsum
        sm.sc.sloff[b4]=run;   sm.sc.slcur[b4]=run;   run+=a0;
        sm.sc.sloff[b4+1]=run; sm.sc.slcur[b4+1]=run; run+=a1;
        sm.sc.sloff[b4+2]=run; sm.sc.slcur[b4+2]=run; run+=a2;
        sm.sc.sloff[b4+3]=run; sm.sc.slcur[b4+3]=run;
        if (a0>0) sm.sc.shc[b4]   = atomicAdd(&bktCur[b4],   a0);
        if (a1>0) sm.sc.shc[b4+1] = atomicAdd(&bktCur[b4+1], a1);
        if (a2>0) sm.sc.shc[b4+2] = atomicAdd(&bktCur[b4+2], a2);
        if (a3>0) sm.sc.shc[b4+3] = atomicAdd(&bktCur[b4+3], a3);
        __syncthreads();
        for (int i=t; i<CH; i+=256){
            long e = e0 + i;
            int slot, keep, s;
            if (e < EDT){ keep = mask_dt[e]; s = ei_dt[e]; slot = ei_dt[EDT+e]; }
            else { long e2 = e-EDT; keep = 1; s = ei_tt[e2]; slot = NT + ei_tt[ETT+e2]; }
            if (keep){
                int b = slot>>9;
                int pos = atomicAdd(&sm.sc.slcur[b], 1);
                sm.sc.stage[pos] = (unsigned)s | ((unsigned)(slot & 511) << 18);
            }
        }
        __syncthreads();
        for (int i=t; i<totKept; i+=256){
            int lo=0, hi=NBKT-1;
            while (lo<hi){ int mid=(lo+hi+1)>>1; if (sm.sc.sloff[mid]<=i) lo=mid; else hi=mid-1; }
            int pos = sm.sc.shc[lo] + (i - sm.sc.sloff[lo]);
            if (pos < BCAP)
                ebuf[(long)lo*BCAP + pos] = sm.sc.stage[i];
        }
        return;
    }
    int isbf = detect_bf16(x_tasks);
    if (blk < NBLK_SCAT + NBLK_STEM){
        // ---- task stem: xt + fused @tt_Wl -> xl_tt ----
        if (t < 192) sm.st.sW[t] = ldf(stem_t_W, t, isbf);
        if (t < 16){ sm.st.sb[t]=ldf(stem_t_b,t,isbf); sm.st.sg[t]=ldf(ln_t_g,t,isbf); sm.st.sbt[t]=ldf(ln_t_b,t,isbf); }
        sm.st.sWl[t]     = ldf(tt_Wl, t,     isbf);
        sm.st.sWl[t+256] = ldf(tt_Wl, t+256, isbf);
        __syncthreads();
        long i = (long)(blk - NBLK_SCAT)*256 + t;
        float f[12];
        if (isbf){
            const uint2* p = (const uint2*)((const char*)x_tasks + i*24);
            uint2 w0=p[0], w1=p[1], w2=p[2];
            unsigned ww[6] = {w0.x,w0.y,w1.x,w1.y,w2.x,w2.y};
            #pragma unroll
            for (int k=0;k<6;k++){ f[2*k]=ulo(ww[k]); f[2*k+1]=uhi(ww[k]); }
        } else {
            const float4* p = (const float4*)((const char*)x_tasks + i*48);
            float4 a=p[0], b2=p[1], c2=p[2];
            f[0]=a.x;  f[1]=a.y;  f[2]=a.z;  f[3]=a.w;
            f[4]=b2.x; f[5]=b2.y; f[6]=b2.z; f[7]=b2.w;
            f[8]=c2.x; f[9]=c2.y; f[10]=c2.z; f[11]=c2.w;
        }
        float h[16];
        #pragma unroll
        for (int c=0;c<16;c++){
            float a = sm.st.sb[c];
            #pragma unroll
            for (int k=0;k<12;k++) a += f[k]*sm.st.sW[k*16+c];
            h[c]=a;
        }
        float mu=0.f;
        #pragma unroll
        for (int c=0;c<16;c++) mu += h[c];
        mu *= (1.f/16.f);
        float var=0.f;
        #pragma unroll
        for (int c=0;c<16;c++){ float d=h[c]-mu; var += d*d; }
        var *= (1.f/16.f);
        float inv = rsqrtf(var + 1e-5f);
        float v[16];
        #pragma unroll
        for (int c=0;c<16;c++){
            float y = sm.st.sg[c]*(h[c]-mu)*inv + sm.st.sbt[c];
            v[c] = fin((y>0.f) ? y : 0.01f*y);
        }
        float4* xp = (float4*)(xt + i*16);
        #pragma unroll
        for (int q=0;q<4;q++) xp[q] = make_float4(v[q*4],v[q*4+1],v[q*4+2],v[q*4+3]);
        float o[32];
        #pragma unroll
        for (int c=0;c<32;c++) o[c]=0.f;
        #pragma unroll
        for (int k=0;k<16;k++){
            float xv=v[k];
            #pragma unroll
            for (int c=0;c<32;c++) o[c] += xv*sm.st.sWl[k*32+c];
        }
        #pragma unroll
        for (int c=0;c<32;c++) o[c] = fin(o[c]);
        uint4* op = (uint4*)(xl_tt + i*16);
        #pragma unroll
        for (int q=0;q<4;q++)
            op[q] = make_uint4(pk2(o[q*8],o[q*8+1]), pk2(o[q*8+2],o[q*8+3]),
                               pk2(o[q*8+4],o[q*8+5]), pk2(o[q*8+6],o[q*8+7]));
    } else {
        // ---- data stem: fused @dt_Wl -> xl_dt ----
        if (t < 80) sm.sd.sW[t] = ldf(stem_d_W, t, isbf);
        if (t < 16){ sm.sd.sb[t]=ldf(stem_d_b,t,isbf); sm.sd.sg[t]=ldf(ln_d_g,t,isbf); sm.sd.sbt[t]=ldf(ln_d_b,t,isbf); }
        sm.sd.sWl[t]     = ldf(dt_Wl, t,     isbf);
        sm.sd.sWl[t+256] = ldf(dt_Wl, t+256, isbf);
        __syncthreads();
        long i = (long)(blk - NBLK_SCAT - NBLK_STEM)*256 + t;
        float f[5];
        #pragma unroll
        for (int k=0;k<5;k++) f[k] = ldf(x_data, i*5+k, isbf);
        float h[16];
        #pragma unroll
        for (int c=0;c<16;c++){
            float a = sm.sd.sb[c];
            #pragma unroll
            for (int k=0;k<5;k++) a += f[k]*sm.sd.sW[k*16+c];
            h[c]=a;
        }
        float mu=0.f;
        #pragma unroll
        for (int c=0;c<16;c++) mu += h[c];
        mu *= (1.f/16.f);
        float var=0.f;
        #pragma unroll
        for (int c=0;c<16;c++){ float d=h[c]-mu; var += d*d; }
        var *= (1.f/16.f);
        float inv = rsqrtf(var + 1e-5f);
        float v[16];
        #pragma unroll
        for (int c=0;c<16;c++){
            float y = sm.sd.sg[c]*(h[c]-mu)*inv + sm.sd.sbt[c];
            v[c] = (y>0.f) ? y : 0.01f*y;
        }
        float o[32];
        #pragma unroll
        for (int c=0;c<32;c++) o[c]=0.f;
        #pragma unroll
        for (int k=0;k<16;k++){
            float xv=v[k];
            #pragma unroll
            for (int c=0;c<32;c++) o[c] += xv*sm.sd.sWl[k*32+c];
        }
        #pragma unroll
        for (int c=0;c<32;c++) o[c] = fin(o[c]);
        uint4* op = (uint4*)(xl_dt + i*16);
        #pragma unroll
        for (int q=0;q<4;q++)
            op[q] = make_uint4(pk2(o[q*8],o[q*8+1]), pk2(o[q*8+2],o[q*8+3]),
                               pk2(o[q*8+4],o[q*8+5]), pk2(o[q*8+6],o[q*8+7]));
    }
}

// ---------------- phase 2: per-bucket LDS CSR + head-serial GAT aggregation ----------------
// FROZEN r7 structure (the round-7 win): sspill combine, 2x unrolled gather
// (4 independent 16B loads in flight; 4x tested r14 = neutral, kept at 2x).
// DO NOT add code to this kernel (r1/r4/r11 regalloc lessons).
__global__ __launch_bounds__(256) void bucket_aggregate_kernel(
    const int* __restrict__ bktCur, const unsigned* __restrict__ ebuf,
    const float* __restrict__ xt,
    const unsigned* __restrict__ xl_dt, const unsigned* __restrict__ xl_tt,
    const void* __restrict__ dt_Wr, const void* __restrict__ tt_Wr,
    const void* __restrict__ dt_att, const void* __restrict__ tt_att,
    float* __restrict__ agg, const void* __restrict__ x_tasks_raw)
{
    __shared__ float sWr[512], satt[32];
    __shared__ int scnt[SPB], soff[SPB], scur[SPB], spart[256];
    __shared__ unsigned slist[BCAP];
    __shared__ float sspill[256*17];
    int t = threadIdx.x;
    int b = blockIdx.x;
    int which = (b >= NBKT/2);
    int isbf = detect_bf16(x_tasks_raw);
    const void* Wr  = which ? tt_Wr  : dt_Wr;
    const void* att = which ? tt_att : dt_att;
    sWr[t]     = ldf(Wr, t,     isbf);
    sWr[t+256] = ldf(Wr, t+256, isbf);
    if (t < 32) satt[t] = ldf(att, t, isbf);
    scnt[t] = 0; scnt[t+256] = 0;
    __syncthreads();
    int base = b*BCAP;
    int ecnt = bktCur[b];
    if (ecnt > BCAP) ecnt = BCAP;
    for (int i=t; i<ecnt; i+=256)
        atomicAdd(&scnt[ebuf[base+i] >> 18], 1);
    __syncthreads();
    int c0 = scnt[2*t], c1 = scnt[2*t+1];
    int ls = c0 + c1;
    spart[t] = ls;
    __syncthreads();
    for (int off=1; off<256; off<<=1){
        int x = spart[t];
        int add = (t>=off) ? spart[t-off] : 0;
        __syncthreads();
        spart[t] = x + add;
        __syncthreads();
    }
    int run = spart[t] - ls;
    soff[2*t] = run; scur[2*t] = run;
    soff[2*t+1] = run + c0; scur[2*t+1] = run + c0;
    __syncthreads();
    for (int i=t; i<ecnt; i+=256){
        unsigned p = ebuf[base+i];
        int pos = atomicAdd(&scur[p >> 18], 1);
        slist[pos] = p & 0x3FFFFu;
    }
    __syncthreads();
    const unsigned* xl = which ? xl_tt : xl_dt;
    #pragma unroll 1
    for (int half=0; half<2; half++){
        int dloc = t + half*256;
        long slot = (long)b*SPB + dloc;
        long d = which ? slot - NT : slot;
        int e0 = soff[dloc], e1 = scur[dloc];
        #pragma unroll 1
        for (int head=0; head<2; head++){
            const float4* xp = (const float4*)(xt + d*16);
            float4 x0=xp[0], x1=xp[1], x2=xp[2], x3=xp[3];
            float xtv[16] = {x0.x,x0.y,x0.z,x0.w, x1.x,x1.y,x1.z,x1.w,
                             x2.x,x2.y,x2.z,x2.w, x3.x,x3.y,x3.z,x3.w};
            float xr[16];
            #pragma unroll
            for (int c=0;c<16;c++) xr[c]=0.f;
            #pragma unroll
            for (int k=0;k<16;k++){
                float xv=xtv[k];
                #pragma unroll
                for (int c=0;c<16;c++) xr[c] += xv*sWr[k*32 + head*16 + c];
            }
            const float* at = satt + head*16;
            float acc[16];
            #pragma unroll
            for (int c=0;c<16;c++) acc[c]=0.f;
            float den=0.f;
            int e = e0;
            // 2x unrolled gather: 4 independent global loads in flight
            for (; e+1 < e1; e += 2){
                long sA = slist[e], sB = slist[e+1];
                const uint4* pA = (const uint4*)(xl + sA*16 + head*8);
                const uint4* pB = (const uint4*)(xl + sB*16 + head*8);
                uint4 ua0 = pA[0], ua1 = pA[1];
                uint4 ub0 = pB[0], ub1 = pB[1];
                float scA = score8(ua0, xr, at) + score8(ua1, xr+8, at+8);
                float scB = score8(ub0, xr, at) + score8(ub1, xr+8, at+8);
                float aA = __expf(fminf(fin(scA), 60.f));
                float aB = __expf(fminf(fin(scB), 60.f));
                den += aA + aB;
                acc8(ua0, aA, acc); acc8(ua1, aA, acc+8);
                acc8(ub0, aB, acc); acc8(ub1, aB, acc+8);
            }
            if (e < e1){
                long s = slist[e];
                const uint4* p = (const uint4*)(xl + s*16 + head*8);
                uint4 u0 = p[0], u1 = p[1];
                float sc = score8(u0, xr, at) + score8(u1, xr+8, at+8);
                float a = __expf(fminf(fin(sc), 60.f));
                den += a;
                acc8(u0, a, acc); acc8(u1, a, acc+8);
            }
            float id = 1.f/fmaxf(den, 1e-16f);
            if (head==0){
                #pragma unroll
                for (int c=0;c<16;c++) sspill[t*17+c] = acc[c]*id;
            } else {
                float4* op = (float4*)(agg + slot*16);
                #pragma unroll
                for (int q=0;q<4;q++){
                    float v[4];
                    #pragma unroll
                    for (int j=0;j<4;j++)
                        v[j] = fin(0.5f*(sspill[t*17+q*4+j] + acc[q*4+j]*id));
                    op[q] = make_float4(v[0],v[1],v[2],v[3]);
                }
            }
        }
    }
}

__device__ __forceinline__ void ln_act16(const float* v, const float* g, const float* b, float* o){
    float mu=0.f;
    #pragma unroll
    for (int c=0;c<16;c++) mu += v[c];
    mu *= (1.f/16.f);
    float var=0.f;
    #pragma unroll
    for (int c=0;c<16;c++){ float d=v[c]-mu; var += d*d; }
    var *= (1.f/16.f);
    float inv = rsqrtf(var + 1e-5f);
    #pragma unroll
    for (int c=0;c<16;c++){
        float y = g[c]*(v[c]-mu)*inv + b[c];
        o[c] = (y>0.f) ? y : 0.01f*y;
    }
}

// ---------------- fuse + pooling + last-block finish ----------------
// r15: all 12 float4 loads (xt, agg_dt, agg_tt) issued UP FRONT (was: agg read
// scalar, after each residual matmul). 192B/thread in flight -> load latency
// hides under the two 16x16 matmuls (same Little's-law lever as r7).
__global__ __launch_bounds__(256) void fuse_pool_kernel(
    const float* __restrict__ xt,
    const float* __restrict__ agg_dt, const float* __restrict__ agg_tt,
    const void* __restrict__ dt_res, const void* __restrict__ dt_bias,
    const void* __restrict__ tt_res, const void* __restrict__ tt_bias,
    const void* __restrict__ ln1g, const void* __restrict__ ln1b,
    const void* __restrict__ ln2g, const void* __restrict__ ln2b,
    const int* __restrict__ b_tasks, const int* __restrict__ ptrg,
    float* __restrict__ pool_sums, float* __restrict__ pool_cnt,
    int* __restrict__ done,
    void* __restrict__ out, const void* __restrict__ x_tasks_raw)
{
    int isbf = detect_bf16(x_tasks_raw);
    __shared__ float sdt[256], stt[256], sdb[16], stb[16], s1g[16], s1b[16], s2g[16], s2b[16];
    __shared__ float swave[4*48];
    __shared__ int sptr[16];
    __shared__ int s_nonuni;
    __shared__ int s_last;
    int t = threadIdx.x;
    sdt[t] = ldf(dt_res, t, isbf);
    stt[t] = ldf(tt_res, t, isbf);
    if (t < 16){
        sdb[t]=ldf(dt_bias,t,isbf); stb[t]=ldf(tt_bias,t,isbf);
        s1g[t]=ldf(ln1g,t,isbf); s1b[t]=ldf(ln1b,t,isbf);
        s2g[t]=ldf(ln2g,t,isbf); s2b[t]=ldf(ln2b,t,isbf);
        sptr[t]=ptrg[t];
    }
    if (t==0) s_nonuni = 0;
    __syncthreads();
    long i = blockIdx.x*256 + t;
    // ---- issue ALL global loads up front: 12 independent float4 ----
    const float4* xp = (const float4*)(xt + i*16);
    const float4* adp = (const float4*)(agg_dt + i*16);
    const float4* atp = (const float4*)(agg_tt + i*16);
    float4 x0=xp[0],  x1=xp[1],  x2=xp[2],  x3=xp[3];
    float4 d0=adp[0], d1=adp[1], d2=adp[2], d3=adp[3];
    float4 t0=atp[0], t1=atp[1], t2=atp[2], t3=atp[3];
    float vals[48];
    float* xv   = vals;
    float* tupd = vals+16;
    float* dupd = vals+32;
    xv[0]=x0.x; xv[1]=x0.y; xv[2]=x0.z; xv[3]=x0.w;
    xv[4]=x1.x; xv[5]=x1.y; xv[6]=x1.z; xv[7]=x1.w;
    xv[8]=x2.x; xv[9]=x2.y; xv[10]=x2.z; xv[11]=x2.w;
    xv[12]=x3.x; xv[13]=x3.y; xv[14]=x3.z; xv[15]=x3.w;
    {
        float agv[16] = {d0.x,d0.y,d0.z,d0.w, d1.x,d1.y,d1.z,d1.w,
                         d2.x,d2.y,d2.z,d2.w, d3.x,d3.y,d3.z,d3.w};
        float v[16];
        #pragma unroll
        for (int c=0;c<16;c++){
            float r = sdb[c];
            #pragma unroll
            for (int k=0;k<16;k++) r += xv[k]*sdt[k*16+c];
            v[c] = fin(agv[c] + r);
        }
        ln_act16(v, s1g, s1b, dupd);
    }
    {
        float agv[16] = {t0.x,t0.y,t0.z,t0.w, t1.x,t1.y,t1.z,t1.w,
                         t2.x,t2.y,t2.z,t2.w, t3.x,t3.y,t3.z,t3.w};
        float v[16];
        #pragma unroll
        for (int c=0;c<16;c++){
            float r = stb[c];
            #pragma unroll
            for (int k=0;k<16;k++) r += xv[k]*stt[k*16+c];
            v[c] = fin(agv[c] + r);
        }
        ln_act16(v, s2g, s2b, tupd);
    }
    #pragma unroll
    for (int j=0;j<48;j++) vals[j] = fin(vals[j]);
    #pragma unroll
    for (int g=0; g<16; g++){
        if (i == sptr[g]){
            for (int j=0;j<48;j++) stf(out, g*96+j, vals[j], isbf);
        }
    }
    int gi = b_tasks[i];
    int g0 = b_tasks[blockIdx.x*256];
    if (gi != g0) s_nonuni = 1;
    __syncthreads();
    if (s_nonuni){
        for (int j=0;j<48;j++) atomicAdd(&pool_sums[gi*48+j], vals[j]);
        atomicAdd(&pool_cnt[gi], 1.f);
    } else {
        int lane = t & 63, wid = t >> 6;
        #pragma unroll
        for (int j=0;j<48;j++){
            float v = vals[j];
            v += __shfl_down(v, 32);
            v += __shfl_down(v, 16);
            v += __shfl_down(v, 8);
            v += __shfl_down(v, 4);
            v += __shfl_down(v, 2);
            v += __shfl_down(v, 1);
            if (lane==0) swave[wid*48+j] = v;
        }
        __syncthreads();
        if (t < 48){
            float s = swave[t] + swave[48+t] + swave[96+t] + swave[144+t];
            atomicAdd(&pool_sums[g0*48+t], s);
        }
        if (t == 0) atomicAdd(&pool_cnt[g0], 256.f);
    }
    // last-block-done: final block computes the 768 pooled means
    __syncthreads();
    if (t == 0){
        __threadfence();
        s_last = (atomicAdd(done, 1) == gridDim.x - 1) ? 1 : 0;
    }
    __syncthreads();
    if (s_last){
        __threadfence();
        for (int j = t; j < 768; j += 256){
            int g = j/48, c = j - g*48;
            stf(out, g*96+48+c, fin(pool_sums[g*48+c]/fmaxf(pool_cnt[g],1.f)), isbf);
        }
    }
}

extern "C" void kernel_launch(void* const* d_in, const int* in_sizes, int n_in,
                              void* d_out, int out_size, void* d_ws, size_t ws_size,
                              hipStream_t stream)
{
    const void* x_tasks  = d_in[0];
    const void* x_data   = d_in[1];
    const void* stem_t_W = d_in[2];
    const void* stem_t_b = d_in[3];
    const void* stem_d_W = d_in[4];
    const void* stem_d_b = d_in[5];
    const void* ln_t_g   = d_in[6];
    const void* ln_t_b   = d_in[7];
    const void* ln_d_g   = d_in[8];
    const void* ln_d_b   = d_in[9];
    const void* dt_Wl    = d_in[10];
    const void* dt_Wr    = d_in[11];
    const void* dt_att   = d_in[12];
    const void* dt_res   = d_in[13];
    const void* dt_bias  = d_in[14];
    const void* tt_Wl    = d_in[15];
    const void* tt_Wr    = d_in[16];
    const void* tt_att   = d_in[17];
    const void* tt_res   = d_in[18];
    const void* tt_bias  = d_in[19];
    const void* ln1_g    = d_in[20];
    const void* ln1_b    = d_in[21];
    const void* ln2_g    = d_in[22];
    const void* ln2_b    = d_in[23];
    const int*  ei_dt    = (const int*)d_in[24];
    const int*  mask_dt  = (const int*)d_in[25];
    const int*  ei_tt    = (const int*)d_in[26];
    const int*  b_tasks  = (const int*)d_in[27];
    const int*  ptrg     = (const int*)d_in[28];

    char* w = (char*)d_ws;
    const size_t MB = 1ull<<20;
    float*    xt        = (float*)(w);              // 16 MB  [NT,16] fp32
    unsigned* xl_dt     = (unsigned*)(w + 16*MB);   // 16 MB  [ND,16] bf16x2-packed
    unsigned* xl_tt     = (unsigned*)(w + 32*MB);   // 16 MB  [NT,16] bf16x2-packed
    float*    agg       = (float*)(w + 48*MB);      // 32 MB  [NSLOT,16] fp32
    unsigned* ebuf      = (unsigned*)(w + 80*MB);   // 12.6 MB (NBKT*BCAP) + slack
    // contiguous control block (zeroed by one memset):
    int*      bktCur    = (int*)  (w + 93*MB);              // 4096 B (relative cursors)
    float*    pool_sums = (float*)(w + 93*MB + 4096);       // 3072 B
    float*    pool_cnt  = (float*)(w + 93*MB + 4096 + 3072);// 64 B
    int*      done      = (int*)  (w + 93*MB + 7232);       // 4 B

    hipMemsetAsync(w + 93*MB, 0, 7296, stream);

    // mega: scatter blocks dispatched first, stems backfill behind
    mega_kernel<<<NBLK_MEGA, 256, 0, stream>>>(
        x_tasks, x_data, stem_t_W, stem_t_b, ln_t_g, ln_t_b,
        stem_d_W, stem_d_b, ln_d_g, ln_d_b, tt_Wl, dt_Wl,
        xt, xl_tt, xl_dt, ei_dt, mask_dt, ei_tt, bktCur, ebuf);

    // per-bucket LDS CSR + head-serial aggregation, 2x unrolled gather (r7 frozen)
    bucket_aggregate_kernel<<<NBKT, 256, 0, stream>>>(bktCur, ebuf, xt, xl_dt, xl_tt,
        dt_Wr, tt_Wr, dt_att, tt_att, agg, x_tasks);

    // fuse + pool + output (r15: up-front vectorized agg loads)
    fuse_pool_kernel<<<NT/256, 256, 0, stream>>>(xt, agg, agg + (long)NT*16,
        dt_res, dt_bias, tt_res, tt_bias, ln1_g, ln1_b, ln2_g, ln2_b,
        b_tasks, ptrg, pool_sums, pool_cnt, done, d_out, x_tasks);
}

// Round 16
// 362.112 us; speedup vs baseline: 1.0174x; 1.0056x over previous
//
#include <hip/hip_runtime.h>
#include <hip/hip_bf16.h>

typedef __hip_bfloat16 bf16;

#define NT 262144
#define ND 262144
#define EDT 2097152
#define ETT 1048576
#define NSLOT (2*NT)            // [0,NT)=d2t dst slots, [NT,2NT)=tt dst slots
#define NE_TOT (EDT+ETT)        // 3145728
#define NBKT 1024               // coarse buckets, bucket = slot>>9
#define SPB 512                 // slots per bucket
#define BCAP 3072               // per-bucket ebuf capacity (mean ~2048)
#define CH 8192                 // edges per scatter block (r7/r9 A/B: 8192 beats 4096)
#define NBLK_SCAT (NE_TOT/CH)   // 384
#define NBLK_STEM (NT/256)      // 1024
#define NBLK_MEGA (2*NBLK_STEM + NBLK_SCAT)

// ---- dual-dtype load/store: isbf==1 -> bf16, else fp32 ----
__device__ __forceinline__ float ldf(const void* p, long i, int isbf){
    if (isbf) return __bfloat162float(((const bf16*)p)[i]);
    return ((const float*)p)[i];
}
__device__ __forceinline__ void stf(void* p, int i, float v, int isbf){
    if (isbf) ((bf16*)p)[i] = __float2bfloat16(v);
    else      ((float*)p)[i] = v;
}
__device__ __forceinline__ float fin(float x){
    return (x==x && x>-3e38f && x<3e38f) ? x : 0.f;
}
// ---- bf16x2 pack/unpack ----
__device__ __forceinline__ unsigned pk2(float a, float b){
    bf16 ha = __float2bfloat16(a), hb = __float2bfloat16(b);
    unsigned short ua = *(unsigned short*)&ha, ub = *(unsigned short*)&hb;
    return ((unsigned)ub<<16) | (unsigned)ua;
}
__device__ __forceinline__ float ulo(unsigned u){ return __uint_as_float(u<<16); }
__device__ __forceinline__ float uhi(unsigned u){ return __uint_as_float(u & 0xffff0000u); }

// block-uniform dtype sniff (proven r2-r15)
__device__ __forceinline__ int detect_bf16(const void* xraw){
    const unsigned* r = (const unsigned*)xraw;
    int c = 0;
    #pragma unroll
    for (int i=0;i<16;i++){
        unsigned e = (r[i] >> 7) & 0xFFu;
        c += (e >= 116u && e <= 134u) ? 1 : 0;
    }
    return c > 8;
}

__device__ __forceinline__ float score8(uint4 u, const float* xr, const float* at){
    float s=0.f, m;
    m = ulo(u.x)+xr[0]; m = m>0.f?m:0.2f*m; s += m*at[0];
    m = uhi(u.x)+xr[1]; m = m>0.f?m:0.2f*m; s += m*at[1];
    m = ulo(u.y)+xr[2]; m = m>0.f?m:0.2f*m; s += m*at[2];
    m = uhi(u.y)+xr[3]; m = m>0.f?m:0.2f*m; s += m*at[3];
    m = ulo(u.z)+xr[4]; m = m>0.f?m:0.2f*m; s += m*at[4];
    m = uhi(u.z)+xr[5]; m = m>0.f?m:0.2f*m; s += m*at[5];
    m = ulo(u.w)+xr[6]; m = m>0.f?m:0.2f*m; s += m*at[6];
    m = uhi(u.w)+xr[7]; m = m>0.f?m:0.2f*m; s += m*at[7];
    return s;
}
__device__ __forceinline__ void acc8(uint4 u, float a, float* acc){
    acc[0] += a*ulo(u.x); acc[1] += a*uhi(u.x);
    acc[2] += a*ulo(u.y); acc[3] += a*uhi(u.y);
    acc[4] += a*ulo(u.z); acc[5] += a*uhi(u.z);
    acc[6] += a*ulo(u.w); acc[7] += a*uhi(u.w);
}

// ---------------- mega kernel: scatter first, then both stems ----------------
// blocks [0,384): scatter   [384,1408): task stem   [1408,2432): data stem
// r16: drain pass is per-owned-bucket (search-free) -- the old 10-step binary
// search was ~10 DEPENDENT LDS loads per element, the longest serial chain in
// the kernel. sloff[] no longer needed (union 46 -> 42KB).
union SmemMega {
    struct { float sW[192], sb[16], sg[16], sbt[16], sWl[512]; } st;   // task stem
    struct { float sW[80],  sb[16], sg[16], sbt[16], sWl[512]; } sd;   // data stem
    struct { int shc[NBKT], slcur[NBKT], spart[256];
             unsigned stage[CH]; } sc;                                  // scatter (41KB)
};

__global__ __launch_bounds__(256) void mega_kernel(
    const void* __restrict__ x_tasks, const void* __restrict__ x_data,
    const void* __restrict__ stem_t_W, const void* __restrict__ stem_t_b,
    const void* __restrict__ ln_t_g, const void* __restrict__ ln_t_b,
    const void* __restrict__ stem_d_W, const void* __restrict__ stem_d_b,
    const void* __restrict__ ln_d_g, const void* __restrict__ ln_d_b,
    const void* __restrict__ tt_Wl, const void* __restrict__ dt_Wl,
    float* __restrict__ xt, unsigned* __restrict__ xl_tt, unsigned* __restrict__ xl_dt,
    const int* __restrict__ ei_dt, const int* __restrict__ mask_dt,
    const int* __restrict__ ei_tt,
    int* __restrict__ bktCur, unsigned* __restrict__ ebuf)
{
    __shared__ SmemMega sm;
    int t = threadIdx.x;
    int blk = blockIdx.x;

    if (blk < NBLK_SCAT){
        // ---- bucket scatter (LDS-staged), packed edge: src | dloc<<18 ----
        long e0 = (long)blk * CH;
        for (int b=t; b<NBKT; b+=256) sm.sc.shc[b]=0;
        __syncthreads();
        for (int i=t; i<CH; i+=256){
            long e = e0 + i;
            int slot, keep;
            if (e < EDT){ keep = mask_dt[e]; slot = ei_dt[EDT+e]; }
            else { long e2 = e-EDT; keep = 1; slot = NT + ei_tt[ETT+e2]; }
            if (keep) atomicAdd(&sm.sc.shc[slot>>9], 1);
        }
        __syncthreads();
        int b4 = t*4;
        int a0=sm.sc.shc[b4], a1=sm.sc.shc[b4+1], a2=sm.sc.shc[b4+2], a3=sm.sc.shc[b4+3];
        int lsum = a0+a1+a2+a3;
        // wave-shfl inclusive scan (register-only) + 1-barrier cross-wave combine
        int lane = t & 63, wid = t >> 6;
        int scan = lsum;
        #pragma unroll
        for (int off=1; off<64; off<<=1){
            int n = __shfl_up(scan, off);
            scan = (lane >= off) ? scan + n : scan;
        }
        if (lane == 63) sm.sc.spart[wid] = scan;
        __syncthreads();
        int wt0 = sm.sc.spart[0], wt1 = sm.sc.spart[1],
            wt2 = sm.sc.spart[2], wt3 = sm.sc.spart[3];
        int wbase = ((wid>0)?wt0:0) + ((wid>1)?wt1:0) + ((wid>2)?wt2:0);
        int run = wbase + scan - lsum;   // exclusive prefix of lsum
        // local stage offsets + global bases kept in REGISTERS (drain is per-bucket)
        int l0 = run;           sm.sc.slcur[b4]   = l0;
        int l1 = l0 + a0;       sm.sc.slcur[b4+1] = l1;
        int l2 = l1 + a1;       sm.sc.slcur[b4+2] = l2;
        int l3 = l2 + a2;       sm.sc.slcur[b4+3] = l3;
        int g0v=0, g1v=0, g2v=0, g3v=0;
        if (a0>0) g0v = atomicAdd(&bktCur[b4],   a0);
        if (a1>0) g1v = atomicAdd(&bktCur[b4+1], a1);
        if (a2>0) g2v = atomicAdd(&bktCur[b4+2], a2);
        if (a3>0) g3v = atomicAdd(&bktCur[b4+3], a3);
        __syncthreads();
        for (int i=t; i<CH; i+=256){
            long e = e0 + i;
            int slot, keep, s;
            if (e < EDT){ keep = mask_dt[e]; s = ei_dt[e]; slot = ei_dt[EDT+e]; }
            else { long e2 = e-EDT; keep = 1; s = ei_tt[e2]; slot = NT + ei_tt[ETT+e2]; }
            if (keep){
                int b = slot>>9;
                int pos = atomicAdd(&sm.sc.slcur[b], 1);
                sm.sc.stage[pos] = (unsigned)s | ((unsigned)(slot & 511) << 18);
            }
        }
        __syncthreads();
        // ---- search-free drain: each thread copies its 4 owned buckets' runs ----
        #pragma unroll
        for (int q=0;q<4;q++){
            int b    = b4 + q;
            int cnt  = (q==0)?a0:(q==1)?a1:(q==2)?a2:a3;
            int lb   = (q==0)?l0:(q==1)?l1:(q==2)?l2:l3;
            int gb   = (q==0)?g0v:(q==1)?g1v:(q==2)?g2v:g3v;
            long ob  = (long)b*BCAP;
            for (int j=0;j<cnt;j++){
                int pos = gb + j;
                if (pos < BCAP)
                    ebuf[ob + pos] = sm.sc.stage[lb + j];
            }
        }
        return;
    }
    int isbf = detect_bf16(x_tasks);
    if (blk < NBLK_SCAT + NBLK_STEM){
        // ---- task stem: xt + fused @tt_Wl -> xl_tt ----
        if (t < 192) sm.st.sW[t] = ldf(stem_t_W, t, isbf);
        if (t < 16){ sm.st.sb[t]=ldf(stem_t_b,t,isbf); sm.st.sg[t]=ldf(ln_t_g,t,isbf); sm.st.sbt[t]=ldf(ln_t_b,t,isbf); }
        sm.st.sWl[t]     = ldf(tt_Wl, t,     isbf);
        sm.st.sWl[t+256] = ldf(tt_Wl, t+256, isbf);
        __syncthreads();
        long i = (long)(blk - NBLK_SCAT)*256 + t;
        float f[12];
        if (isbf){
            const uint2* p = (const uint2*)((const char*)x_tasks + i*24);
            uint2 w0=p[0], w1=p[1], w2=p[2];
            unsigned ww[6] = {w0.x,w0.y,w1.x,w1.y,w2.x,w2.y};
            #pragma unroll
            for (int k=0;k<6;k++){ f[2*k]=ulo(ww[k]); f[2*k+1]=uhi(ww[k]); }
        } else {
            const float4* p = (const float4*)((const char*)x_tasks + i*48);
            float4 a=p[0], b2=p[1], c2=p[2];
            f[0]=a.x;  f[1]=a.y;  f[2]=a.z;  f[3]=a.w;
            f[4]=b2.x; f[5]=b2.y; f[6]=b2.z; f[7]=b2.w;
            f[8]=c2.x; f[9]=c2.y; f[10]=c2.z; f[11]=c2.w;
        }
        float h[16];
        #pragma unroll
        for (int c=0;c<16;c++){
            float a = sm.st.sb[c];
            #pragma unroll
            for (int k=0;k<12;k++) a += f[k]*sm.st.sW[k*16+c];
            h[c]=a;
        }
        float mu=0.f;
        #pragma unroll
        for (int c=0;c<16;c++) mu += h[c];
        mu *= (1.f/16.f);
        float var=0.f;
        #pragma unroll
        for (int c=0;c<16;c++){ float d=h[c]-mu; var += d*d; }
        var *= (1.f/16.f);
        float inv = rsqrtf(var + 1e-5f);
        float v[16];
        #pragma unroll
        for (int c=0;c<16;c++){
            float y = sm.st.sg[c]*(h[c]-mu)*inv + sm.st.sbt[c];
            v[c] = fin((y>0.f) ? y : 0.01f*y);
        }
        float4* xp = (float4*)(xt + i*16);
        #pragma unroll
        for (int q=0;q<4;q++) xp[q] = make_float4(v[q*4],v[q*4+1],v[q*4+2],v[q*4+3]);
        float o[32];
        #pragma unroll
        for (int c=0;c<32;c++) o[c]=0.f;
        #pragma unroll
        for (int k=0;k<16;k++){
            float xv=v[k];
            #pragma unroll
            for (int c=0;c<32;c++) o[c] += xv*sm.st.sWl[k*32+c];
        }
        #pragma unroll
        for (int c=0;c<32;c++) o[c] = fin(o[c]);
        uint4* op = (uint4*)(xl_tt + i*16);
        #pragma unroll
        for (int q=0;q<4;q++)
            op[q] = make_uint4(pk2(o[q*8],o[q*8+1]), pk2(o[q*8+2],o[q*8+3]),
                               pk2(o[q*8+4],o[q*8+5]), pk2(o[q*8+6],o[q*8+7]));
    } else {
        // ---- data stem: fused @dt_Wl -> xl_dt ----
        if (t < 80) sm.sd.sW[t] = ldf(stem_d_W, t, isbf);
        if (t < 16){ sm.sd.sb[t]=ldf(stem_d_b,t,isbf); sm.sd.sg[t]=ldf(ln_d_g,t,isbf); sm.sd.sbt[t]=ldf(ln_d_b,t,isbf); }
        sm.sd.sWl[t]     = ldf(dt_Wl, t,     isbf);
        sm.sd.sWl[t+256] = ldf(dt_Wl, t+256, isbf);
        __syncthreads();
        long i = (long)(blk - NBLK_SCAT - NBLK_STEM)*256 + t;
        float f[5];
        #pragma unroll
        for (int k=0;k<5;k++) f[k] = ldf(x_data, i*5+k, isbf);
        float h[16];
        #pragma unroll
        for (int c=0;c<16;c++){
            float a = sm.sd.sb[c];
            #pragma unroll
            for (int k=0;k<5;k++) a += f[k]*sm.sd.sW[k*16+c];
            h[c]=a;
        }
        float mu=0.f;
        #pragma unroll
        for (int c=0;c<16;c++) mu += h[c];
        mu *= (1.f/16.f);
        float var=0.f;
        #pragma unroll
        for (int c=0;c<16;c++){ float d=h[c]-mu; var += d*d; }
        var *= (1.f/16.f);
        float inv = rsqrtf(var + 1e-5f);
        float v[16];
        #pragma unroll
        for (int c=0;c<16;c++){
            float y = sm.sd.sg[c]*(h[c]-mu)*inv + sm.sd.sbt[c];
            v[c] = (y>0.f) ? y : 0.01f*y;
        }
        float o[32];
        #pragma unroll
        for (int c=0;c<32;c++) o[c]=0.f;
        #pragma unroll
        for (int k=0;k<16;k++){
            float xv=v[k];
            #pragma unroll
            for (int c=0;c<32;c++) o[c] += xv*sm.sd.sWl[k*32+c];
        }
        #pragma unroll
        for (int c=0;c<32;c++) o[c] = fin(o[c]);
        uint4* op = (uint4*)(xl_dt + i*16);
        #pragma unroll
        for (int q=0;q<4;q++)
            op[q] = make_uint4(pk2(o[q*8],o[q*8+1]), pk2(o[q*8+2],o[q*8+3]),
                               pk2(o[q*8+4],o[q*8+5]), pk2(o[q*8+6],o[q*8+7]));
    }
}

// ---------------- phase 2: per-bucket LDS CSR + head-serial GAT aggregation ----------------
// FROZEN r7 structure (the round-7 win): sspill combine, 2x unrolled gather
// (4 independent 16B loads in flight; 4x tested r14 = neutral, kept at 2x).
// DO NOT add code to this kernel (r1/r4/r11 regalloc lessons).
__global__ __launch_bounds__(256) void bucket_aggregate_kernel(
    const int* __restrict__ bktCur, const unsigned* __restrict__ ebuf,
    const float* __restrict__ xt,
    const unsigned* __restrict__ xl_dt, const unsigned* __restrict__ xl_tt,
    const void* __restrict__ dt_Wr, const void* __restrict__ tt_Wr,
    const void* __restrict__ dt_att, const void* __restrict__ tt_att,
    float* __restrict__ agg, const void* __restrict__ x_tasks_raw)
{
    __shared__ float sWr[512], satt[32];
    __shared__ int scnt[SPB], soff[SPB], scur[SPB], spart[256];
    __shared__ unsigned slist[BCAP];
    __shared__ float sspill[256*17];
    int t = threadIdx.x;
    int b = blockIdx.x;
    int which = (b >= NBKT/2);
    int isbf = detect_bf16(x_tasks_raw);
    const void* Wr  = which ? tt_Wr  : dt_Wr;
    const void* att = which ? tt_att : dt_att;
    sWr[t]     = ldf(Wr, t,     isbf);
    sWr[t+256] = ldf(Wr, t+256, isbf);
    if (t < 32) satt[t] = ldf(att, t, isbf);
    scnt[t] = 0; scnt[t+256] = 0;
    __syncthreads();
    int base = b*BCAP;
    int ecnt = bktCur[b];
    if (ecnt > BCAP) ecnt = BCAP;
    for (int i=t; i<ecnt; i+=256)
        atomicAdd(&scnt[ebuf[base+i] >> 18], 1);
    __syncthreads();
    int c0 = scnt[2*t], c1 = scnt[2*t+1];
    int ls = c0 + c1;
    spart[t] = ls;
    __syncthreads();
    for (int off=1; off<256; off<<=1){
        int x = spart[t];
        int add = (t>=off) ? spart[t-off] : 0;
        __syncthreads();
        spart[t] = x + add;
        __syncthreads();
    }
    int run = spart[t] - ls;
    soff[2*t] = run; scur[2*t] = run;
    soff[2*t+1] = run + c0; scur[2*t+1] = run + c0;
    __syncthreads();
    for (int i=t; i<ecnt; i+=256){
        unsigned p = ebuf[base+i];
        int pos = atomicAdd(&scur[p >> 18], 1);
        slist[pos] = p & 0x3FFFFu;
    }
    __syncthreads();
    const unsigned* xl = which ? xl_tt : xl_dt;
    #pragma unroll 1
    for (int half=0; half<2; half++){
        int dloc = t + half*256;
        long slot = (long)b*SPB + dloc;
        long d = which ? slot - NT : slot;
        int e0 = soff[dloc], e1 = scur[dloc];
        #pragma unroll 1
        for (int head=0; head<2; head++){
            const float4* xp = (const float4*)(xt + d*16);
            float4 x0=xp[0], x1=xp[1], x2=xp[2], x3=xp[3];
            float xtv[16] = {x0.x,x0.y,x0.z,x0.w, x1.x,x1.y,x1.z,x1.w,
                             x2.x,x2.y,x2.z,x2.w, x3.x,x3.y,x3.z,x3.w};
            float xr[16];
            #pragma unroll
            for (int c=0;c<16;c++) xr[c]=0.f;
            #pragma unroll
            for (int k=0;k<16;k++){
                float xv=xtv[k];
                #pragma unroll
                for (int c=0;c<16;c++) xr[c] += xv*sWr[k*32 + head*16 + c];
            }
            const float* at = satt + head*16;
            float acc[16];
            #pragma unroll
            for (int c=0;c<16;c++) acc[c]=0.f;
            float den=0.f;
            int e = e0;
            // 2x unrolled gather: 4 independent global loads in flight
            for (; e+1 < e1; e += 2){
                long sA = slist[e], sB = slist[e+1];
                const uint4* pA = (const uint4*)(xl + sA*16 + head*8);
                const uint4* pB = (const uint4*)(xl + sB*16 + head*8);
                uint4 ua0 = pA[0], ua1 = pA[1];
                uint4 ub0 = pB[0], ub1 = pB[1];
                float scA = score8(ua0, xr, at) + score8(ua1, xr+8, at+8);
                float scB = score8(ub0, xr, at) + score8(ub1, xr+8, at+8);
                float aA = __expf(fminf(fin(scA), 60.f));
                float aB = __expf(fminf(fin(scB), 60.f));
                den += aA + aB;
                acc8(ua0, aA, acc); acc8(ua1, aA, acc+8);
                acc8(ub0, aB, acc); acc8(ub1, aB, acc+8);
            }
            if (e < e1){
                long s = slist[e];
                const uint4* p = (const uint4*)(xl + s*16 + head*8);
                uint4 u0 = p[0], u1 = p[1];
                float sc = score8(u0, xr, at) + score8(u1, xr+8, at+8);
                float a = __expf(fminf(fin(sc), 60.f));
                den += a;
                acc8(u0, a, acc); acc8(u1, a, acc+8);
            }
            float id = 1.f/fmaxf(den, 1e-16f);
            if (head==0){
                #pragma unroll
                for (int c=0;c<16;c++) sspill[t*17+c] = acc[c]*id;
            } else {
                float4* op = (float4*)(agg + slot*16);
                #pragma unroll
                for (int q=0;q<4;q++){
                    float v[4];
                    #pragma unroll
                    for (int j=0;j<4;j++)
                        v[j] = fin(0.5f*(sspill[t*17+q*4+j] + acc[q*4+j]*id));
                    op[q] = make_float4(v[0],v[1],v[2],v[3]);
                }
            }
        }
    }
}

__device__ __forceinline__ void ln_act16(const float* v, const float* g, const float* b, float* o){
    float mu=0.f;
    #pragma unroll
    for (int c=0;c<16;c++) mu += v[c];
    mu *= (1.f/16.f);
    float var=0.f;
    #pragma unroll
    for (int c=0;c<16;c++){ float d=v[c]-mu; var += d*d; }
    var *= (1.f/16.f);
    float inv = rsqrtf(var + 1e-5f);
    #pragma unroll
    for (int c=0;c<16;c++){
        float y = g[c]*(v[c]-mu)*inv + b[c];
        o[c] = (y>0.f) ? y : 0.01f*y;
    }
}

// ---------------- fuse + pooling + last-block finish ----------------
// r15 win kept: all 12 float4 loads (xt, agg_dt, agg_tt) issued UP FRONT.
__global__ __launch_bounds__(256) void fuse_pool_kernel(
    const float* __restrict__ xt,
    const float* __restrict__ agg_dt, const float* __restrict__ agg_tt,
    const void* __restrict__ dt_res, const void* __restrict__ dt_bias,
    const void* __restrict__ tt_res, const void* __restrict__ tt_bias,
    const void* __restrict__ ln1g, const void* __restrict__ ln1b,
    const void* __restrict__ ln2g, const void* __restrict__ ln2b,
    const int* __restrict__ b_tasks, const int* __restrict__ ptrg,
    float* __restrict__ pool_sums, float* __restrict__ pool_cnt,
    int* __restrict__ done,
    void* __restrict__ out, const void* __restrict__ x_tasks_raw)
{
    int isbf = detect_bf16(x_tasks_raw);
    __shared__ float sdt[256], stt[256], sdb[16], stb[16], s1g[16], s1b[16], s2g[16], s2b[16];
    __shared__ float swave[4*48];
    __shared__ int sptr[16];
    __shared__ int s_nonuni;
    __shared__ int s_last;
    int t = threadIdx.x;
    sdt[t] = ldf(dt_res, t, isbf);
    stt[t] = ldf(tt_res, t, isbf);
    if (t < 16){
        sdb[t]=ldf(dt_bias,t,isbf); stb[t]=ldf(tt_bias,t,isbf);
        s1g[t]=ldf(ln1g,t,isbf); s1b[t]=ldf(ln1b,t,isbf);
        s2g[t]=ldf(ln2g,t,isbf); s2b[t]=ldf(ln2b,t,isbf);
        sptr[t]=ptrg[t];
    }
    if (t==0) s_nonuni = 0;
    __syncthreads();
    long i = blockIdx.x*256 + t;
    // ---- issue ALL global loads up front: 12 independent float4 ----
    const float4* xp = (const float4*)(xt + i*16);
    const float4* adp = (const float4*)(agg_dt + i*16);
    const float4* atp = (const float4*)(agg_tt + i*16);
    float4 x0=xp[0],  x1=xp[1],  x2=xp[2],  x3=xp[3];
    float4 d0=adp[0], d1=adp[1], d2=adp[2], d3=adp[3];
    float4 t0=atp[0], t1=atp[1], t2=atp[2], t3=atp[3];
    float vals[48];
    float* xv   = vals;
    float* tupd = vals+16;
    float* dupd = vals+32;
    xv[0]=x0.x; xv[1]=x0.y; xv[2]=x0.z; xv[3]=x0.w;
    xv[4]=x1.x; xv[5]=x1.y; xv[6]=x1.z; xv[7]=x1.w;
    xv[8]=x2.x; xv[9]=x2.y; xv[10]=x2.z; xv[11]=x2.w;
    xv[12]=x3.x; xv[13]=x3.y; xv[14]=x3.z; xv[15]=x3.w;
    {
        float agv[16] = {d0.x,d0.y,d0.z,d0.w, d1.x,d1.y,d1.z,d1.w,
                         d2.x,d2.y,d2.z,d2.w, d3.x,d3.y,d3.z,d3.w};
        float v[16];
        #pragma unroll
        for (int c=0;c<16;c++){
            float r = sdb[c];
            #pragma unroll
            for (int k=0;k<16;k++) r += xv[k]*sdt[k*16+c];
            v[c] = fin(agv[c] + r);
        }
        ln_act16(v, s1g, s1b, dupd);
    }
    {
        float agv[16] = {t0.x,t0.y,t0.z,t0.w, t1.x,t1.y,t1.z,t1.w,
                         t2.x,t2.y,t2.z,t2.w, t3.x,t3.y,t3.z,t3.w};
        float v[16];
        #pragma unroll
        for (int c=0;c<16;c++){
            float r = stb[c];
            #pragma unroll
            for (int k=0;k<16;k++) r += xv[k]*stt[k*16+c];
            v[c] = fin(agv[c] + r);
        }
        ln_act16(v, s2g, s2b, tupd);
    }
    #pragma unroll
    for (int j=0;j<48;j++) vals[j] = fin(vals[j]);
    #pragma unroll
    for (int g=0; g<16; g++){
        if (i == sptr[g]){
            for (int j=0;j<48;j++) stf(out, g*96+j, vals[j], isbf);
        }
    }
    int gi = b_tasks[i];
    int g0 = b_tasks[blockIdx.x*256];
    if (gi != g0) s_nonuni = 1;
    __syncthreads();
    if (s_nonuni){
        for (int j=0;j<48;j++) atomicAdd(&pool_sums[gi*48+j], vals[j]);
        atomicAdd(&pool_cnt[gi], 1.f);
    } else {
        int lane = t & 63, wid = t >> 6;
        #pragma unroll
        for (int j=0;j<48;j++){
            float v = vals[j];
            v += __shfl_down(v, 32);
            v += __shfl_down(v, 16);
            v += __shfl_down(v, 8);
            v += __shfl_down(v, 4);
            v += __shfl_down(v, 2);
            v += __shfl_down(v, 1);
            if (lane==0) swave[wid*48+j] = v;
        }
        __syncthreads();
        if (t < 48){
            float s = swave[t] + swave[48+t] + swave[96+t] + swave[144+t];
            atomicAdd(&pool_sums[g0*48+t], s);
        }
        if (t == 0) atomicAdd(&pool_cnt[g0], 256.f);
    }
    // last-block-done: final block computes the 768 pooled means
    __syncthreads();
    if (t == 0){
        __threadfence();
        s_last = (atomicAdd(done, 1) == gridDim.x - 1) ? 1 : 0;
    }
    __syncthreads();
    if (s_last){
        __threadfence();
        for (int j = t; j < 768; j += 256){
            int g = j/48, c = j - g*48;
            stf(out, g*96+48+c, fin(pool_sums[g*48+c]/fmaxf(pool_cnt[g],1.f)), isbf);
        }
    }
}

extern "C" void kernel_launch(void* const* d_in, const int* in_sizes, int n_in,
                              void* d_out, int out_size, void* d_ws, size_t ws_size,
                              hipStream_t stream)
{
    const void* x_tasks  = d_in[0];
    const void* x_data   = d_in[1];
    const void* stem_t_W = d_in[2];
    const void* stem_t_b = d_in[3];
    const void* stem_d_W = d_in[4];
    const void* stem_d_b = d_in[5];
    const void* ln_t_g   = d_in[6];
    const void* ln_t_b   = d_in[7];
    const void* ln_d_g   = d_in[8];
    const void* ln_d_b   = d_in[9];
    const void* dt_Wl    = d_in[10];
    const void* dt_Wr    = d_in[11];
    const void* dt_att   = d_in[12];
    const void* dt_res   = d_in[13];
    const void* dt_bias  = d_in[14];
    const void* tt_Wl    = d_in[15];
    const void* tt_Wr    = d_in[16];
    const void* tt_att   = d_in[17];
    const void* tt_res   = d_in[18];
    const void* tt_bias  = d_in[19];
    const void* ln1_g    = d_in[20];
    const void* ln1_b    = d_in[21];
    const void* ln2_g    = d_in[22];
    const void* ln2_b    = d_in[23];
    const int*  ei_dt    = (const int*)d_in[24];
    const int*  mask_dt  = (const int*)d_in[25];
    const int*  ei_tt    = (const int*)d_in[26];
    const int*  b_tasks  = (const int*)d_in[27];
    const int*  ptrg     = (const int*)d_in[28];

    char* w = (char*)d_ws;
    const size_t MB = 1ull<<20;
    float*    xt        = (float*)(w);              // 16 MB  [NT,16] fp32
    unsigned* xl_dt     = (unsigned*)(w + 16*MB);   // 16 MB  [ND,16] bf16x2-packed
    unsigned* xl_tt     = (unsigned*)(w + 32*MB);   // 16 MB  [NT,16] bf16x2-packed
    float*    agg       = (float*)(w + 48*MB);      // 32 MB  [NSLOT,16] fp32
    unsigned* ebuf      = (unsigned*)(w + 80*MB);   // 12.6 MB (NBKT*BCAP) + slack
    // contiguous control block (zeroed by one memset):
    int*      bktCur    = (int*)  (w + 93*MB);              // 4096 B (relative cursors)
    float*    pool_sums = (float*)(w + 93*MB + 4096);       // 3072 B
    float*    pool_cnt  = (float*)(w + 93*MB + 4096 + 3072);// 64 B
    int*      done      = (int*)  (w + 93*MB + 7232);       // 4 B

    hipMemsetAsync(w + 93*MB, 0, 7296, stream);

    // mega: scatter blocks dispatched first, stems backfill behind
    mega_kernel<<<NBLK_MEGA, 256, 0, stream>>>(
        x_tasks, x_data, stem_t_W, stem_t_b, ln_t_g, ln_t_b,
        stem_d_W, stem_d_b, ln_d_g, ln_d_b, tt_Wl, dt_Wl,
        xt, xl_tt, xl_dt, ei_dt, mask_dt, ei_tt, bktCur, ebuf);

    // per-bucket LDS CSR + head-serial aggregation, 2x unrolled gather (r7 frozen)
    bucket_aggregate_kernel<<<NBKT, 256, 0, stream>>>(bktCur, ebuf, xt, xl_dt, xl_tt,
        dt_Wr, tt_Wr, dt_att, tt_att, agg, x_tasks);

    // fuse + pool + output (r15: up-front vectorized agg loads)
    fuse_pool_kernel<<<NT/256, 256, 0, stream>>>(xt, agg, agg + (long)NT*16,
        dt_res, dt_bias, tt_res, tt_bias, ln1_g, ln1_b, ln2_g, ln2_b,
        b_tasks, ptrg, pool_sums, pool_cnt, done, d_out, x_tasks);
}